// Round 2
// baseline (131.814 us; speedup 1.0000x reference)
//
#include <hip/hip_runtime.h>
#include <math.h>

#define A_ 64
#define T_ 32
#define B_ 64
#define V_ 12
#define D_ 512
#define TAUF 100.0f
#define BQ 4               // b's per block
#define TSTRIDE 514        // text LDS row stride (floats): float2-aligned, 2-way banks (free)

// K1: inverse L2 norms of all text (2048) and video (768) rows -> ws
__global__ void norm_kernel(const float* __restrict__ text,
                            const float* __restrict__ video,
                            float* __restrict__ inv)
{
    int r = blockIdx.x;
    const float* src = (r < A_ * T_) ? (text + (size_t)r * D_)
                                     : (video + (size_t)(r - A_ * T_) * D_);
    int tid = threadIdx.x; // 128 threads, one float4 each (512 floats)
    float4 x = ((const float4*)src)[tid];
    float ss = x.x * x.x + x.y * x.y + x.z * x.z + x.w * x.w;
    for (int m = 32; m >= 1; m >>= 1) ss += __shfl_xor(ss, m);
    __shared__ float red[2];
    if ((tid & 63) == 0) red[tid >> 6] = ss;
    __syncthreads();
    if (tid == 0) {
        float s = red[0] + red[1];
        inv[r] = 1.0f / fmaxf(sqrtf(s), 1e-6f);
    }
}

// K2: one block per (a, 4 consecutive b). 384 threads.
// Dot phase: thread -> (t = tid&31, group g = tid>>5: bq = g/3, vq = g%3),
// computes 4 outputs (t, vq*4..vq*4+3) for video b = bg*4+bq.
__global__ __launch_bounds__(384)
void fused_kernel(const float* __restrict__ text,
                  const float* __restrict__ video,
                  const int* __restrict__ mask,
                  const float* __restrict__ inv,
                  float* __restrict__ out)
{
    const int a  = blockIdx.y;
    const int bg = blockIdx.x;          // 0..15
    const int tid = threadIdx.x;        // 0..383

    __shared__ __align__(16) float tsh[T_ * TSTRIDE];   // normalized text
    __shared__ __align__(16) float Lsh[BQ][T_][V_];     // raw logits
    __shared__ float v2t_sh[BQ][V_];
    __shared__ float w2_sh[BQ][T_];
    __shared__ float wv_sh[BQ][V_];
    __shared__ float stats[BQ][2];
    __shared__ float redD[BQ][6];
    __shared__ int   msh[T_];

    // ---- stage normalized text rows into LDS (coalesced float4, float2 writes) ----
    {
        const float4* tp = (const float4*)(text + (size_t)a * T_ * D_);
        const float*  invt = inv + a * T_;
        for (int idx = tid; idx < T_ * (D_ / 4); idx += 384) {
            int row = idx >> 7;
            int col = idx & 127;
            float4 x = tp[idx];
            float s = invt[row];
            float* dst = &tsh[row * TSTRIDE + col * 4];
            ((float2*)dst)[0] = make_float2(x.x * s, x.y * s);
            ((float2*)dst)[1] = make_float2(x.z * s, x.w * s);
        }
        if (tid < T_) msh[tid] = mask[a * T_ + tid];
    }
    __syncthreads();

    const int g  = tid >> 5;            // 0..11
    const int t  = tid & 31;
    const int bq = g / 3;               // 0..3
    const int vq = g - bq * 3;          // 0..2
    const int b  = bg * BQ + bq;

    // ---- dot phase: 16 FMAs per 16B of LDS text ----
    {
        const float2* trow = (const float2*)&tsh[t * TSTRIDE];
        const float4* vr0 = (const float4*)(video + ((size_t)b * V_ + vq * 4) * D_);
        const float4* vr1 = vr0 + 128;
        const float4* vr2 = vr0 + 256;
        const float4* vr3 = vr0 + 384;
        float4 ac0 = {0,0,0,0}, ac1 = {0,0,0,0}, ac2 = {0,0,0,0}, ac3 = {0,0,0,0};
        #pragma unroll 4
        for (int k = 0; k < 128; ++k) {
            float2 xa = trow[2 * k];
            float2 xb = trow[2 * k + 1];
            float4 y0 = vr0[k];
            float4 y1 = vr1[k];
            float4 y2 = vr2[k];
            float4 y3 = vr3[k];
            ac0.x += xa.x * y0.x; ac0.y += xa.y * y0.y; ac0.z += xb.x * y0.z; ac0.w += xb.y * y0.w;
            ac1.x += xa.x * y1.x; ac1.y += xa.y * y1.y; ac1.z += xb.x * y1.z; ac1.w += xb.y * y1.w;
            ac2.x += xa.x * y2.x; ac2.y += xa.y * y2.y; ac2.z += xb.x * y2.z; ac2.w += xb.y * y2.w;
            ac3.x += xa.x * y3.x; ac3.y += xa.y * y3.y; ac3.z += xb.x * y3.z; ac3.w += xb.y * y3.w;
        }
        const float* invv = inv + A_ * T_ + b * V_ + vq * 4;
        float4 Lv;
        Lv.x = ((ac0.x + ac0.y) + (ac0.z + ac0.w)) * invv[0];
        Lv.y = ((ac1.x + ac1.y) + (ac1.z + ac1.w)) * invv[1];
        Lv.z = ((ac2.x + ac2.y) + (ac2.z + ac2.w)) * invv[2];
        Lv.w = ((ac3.x + ac3.y) + (ac3.z + ac3.w)) * invv[3];
        *(float4*)&Lsh[bq][t][vq * 4] = Lv;
    }
    __syncthreads();

    // ---- Phase B: row softmax -> t2v (in reg); column masked softmax -> v2t_sh ----
    float t2v_val = 0.0f;
    if (tid < 128) {
        int bq2 = tid >> 5, t2 = tid & 31;
        const float* Lr = Lsh[bq2][t2];
        float l[V_];
        #pragma unroll
        for (int j = 0; j < V_; ++j) l[j] = Lr[j];
        if (msh[t2]) {
            float m = -1e30f;
            #pragma unroll
            for (int j = 0; j < V_; ++j) m = fmaxf(m, l[j]);
            float s = 0.f, num = 0.f;
            #pragma unroll
            for (int j = 0; j < V_; ++j) {
                float e = expf(TAUF * (l[j] - m));
                s += e; num += e * l[j];
            }
            t2v_val = num / s;
        } else {
            // softmax of all-zero logits = uniform -> mean of raw logits
            float s = 0.f;
            #pragma unroll
            for (int j = 0; j < V_; ++j) s += l[j];
            t2v_val = s * (1.0f / V_);
        }
    } else if (tid < 128 + BQ * V_) {
        int idx = tid - 128;
        int bq2 = idx / V_, v2 = idx - bq2 * V_;
        float m = -1e30f;
        for (int j = 0; j < T_; ++j) {
            float Lm = msh[j] ? Lsh[bq2][j][v2] : 0.0f;
            if (Lm != 0.0f) m = fmaxf(m, Lm);
        }
        float s = 0.f, num = 0.f;
        for (int j = 0; j < T_; ++j) {
            float Lraw = Lsh[bq2][j][v2];
            float Lm = msh[j] ? Lraw : 0.0f;
            if (Lm != 0.0f) {
                float e = expf(TAUF * (Lm - m));
                s += e; num += e * Lraw;
            }
        }
        v2t_sh[bq2][v2] = num / s;
    }
    __syncthreads();

    // ---- Phase C: tps2 weights (half-wave shuffle reduce) and vps2 weights ----
    if (tid < 128) {
        int bq2 = tid >> 5, t2 = tid & 31;
        bool ex = (t2v_val == 0.0f);
        float x = ex ? -1e30f : t2v_val;
        #pragma unroll
        for (int m = 16; m >= 1; m >>= 1) x = fmaxf(x, __shfl_xor(x, m));
        float w = ex ? 0.0f : expf(TAUF * (t2v_val - x));
        float s = w;
        #pragma unroll
        for (int m = 16; m >= 1; m >>= 1) s += __shfl_xor(s, m);
        w2_sh[bq2][t2] = w;
        if (t2 == 0) stats[bq2][0] = s;
    } else if (tid < 128 + BQ * V_) {
        int idx = tid - 128;
        int bq2 = idx / V_, v2 = idx - bq2 * V_;
        float m = -1e30f;
        #pragma unroll
        for (int j = 0; j < V_; ++j) m = fmaxf(m, v2t_sh[bq2][j]);
        float s = 0.f;
        #pragma unroll
        for (int j = 0; j < V_; ++j) s += expf(TAUF * (v2t_sh[bq2][j] - m));
        wv_sh[bq2][v2] = expf(TAUF * (v2t_sh[bq2][v2] - m));
        if (v2 == 0) stats[bq2][1] = s;
    }
    __syncthreads();

    // ---- Phase D: out = sum_{t,v} w2[t]*wv[v]*L[t,v] / (W2*Wv) for each bq ----
    {
        int vD = tid >> 5;              // 0..11
        float p0 = w2_sh[0][t] * wv_sh[0][vD] * Lsh[0][t][vD];
        float p1 = w2_sh[1][t] * wv_sh[1][vD] * Lsh[1][t][vD];
        float p2 = w2_sh[2][t] * wv_sh[2][vD] * Lsh[2][t][vD];
        float p3 = w2_sh[3][t] * wv_sh[3][vD] * Lsh[3][t][vD];
        #pragma unroll
        for (int m = 32; m >= 1; m >>= 1) {
            p0 += __shfl_xor(p0, m);
            p1 += __shfl_xor(p1, m);
            p2 += __shfl_xor(p2, m);
            p3 += __shfl_xor(p3, m);
        }
        if ((tid & 63) == 0) {
            int w = tid >> 6;
            redD[0][w] = p0; redD[1][w] = p1; redD[2][w] = p2; redD[3][w] = p3;
        }
    }
    __syncthreads();
    if (tid < BQ) {
        float s = 0.f;
        #pragma unroll
        for (int w = 0; w < 6; ++w) s += redD[tid][w];
        out[a * B_ + bg * BQ + tid] = s / (stats[tid][0] * stats[tid][1]);
    }
}

extern "C" void kernel_launch(void* const* d_in, const int* in_sizes, int n_in,
                              void* d_out, int out_size, void* d_ws, size_t ws_size,
                              hipStream_t stream) {
    const float* text  = (const float*)d_in[0];
    const float* video = (const float*)d_in[1];
    const int*   mask  = (const int*)d_in[2];
    float* out = (float*)d_out;
    float* inv = (float*)d_ws;   // 2816 floats

    norm_kernel<<<A_ * T_ + B_ * V_, 128, 0, stream>>>(text, video, inv);
    fused_kernel<<<dim3(B_ / BQ, A_), 384, 0, stream>>>(text, video, mask, inv, out);
}